// Round 4
// baseline (119.930 us; speedup 1.0000x reference)
//
#include <hip/hip_runtime.h>

#define HH 512
#define WW 512
#define HO 502
#define WO 502
#define KS 11
#define OTH 32                 // output tile rows
#define RPT 8                  // v-rows per thread in phase 1 (4 groups)
#define NR  (RPT + KS - 1)     // 18 input rows per thread
#define OTW 52                 // output tile cols
#define VW  62                 // v-buffer cols = OTW + KS - 1
#define RS  33                 // padded row-stride (dwords) per column
#define CHS (VW * RS)          // 2046 dwords per channel
#define CPT 7                  // output cols per thread in phase 2

// symmetric gaussian lookup, k compile-time
#define GW(k) g[(k) < 6 ? (k) : 10 - (k)]

__global__ __launch_bounds__(256)
__attribute__((amdgpu_waves_per_eu(4, 4)))
void ssim_sep_kernel(
    const float* __restrict__ img1, const float* __restrict__ img2,
    const float* __restrict__ win, double* __restrict__ acc)
{
    __shared__ float vbuf[5 * CHS];   // 40,920 B -> 4 blocks/CU

    const int tid = threadIdx.x;
    const int tile_c0 = blockIdx.x * OTW;
    const int tile_r0 = blockIdx.y * OTH;
    const size_t base = (size_t)blockIdx.z * (HH * WW);

    // 1-D gaussian from separable 2-D window: g[k] = w[5][k]/sqrt(w[5][5]); symmetric
    float g[6];
    {
        double inv = 1.0 / sqrt((double)win[5 * KS + 5]);
        #pragma unroll
        for (int k = 0; k < 6; ++k)
            g[k] = (float)((double)win[5 * KS + k] * inv);
    }

    // ---------- phase 1: vertical conv, global -> registers -> LDS (transposed) ----------
    {
        const int lane = tid & 63;          // column within v tile
        // wave-uniform first row: SGPR row addressing, SALU stepping
        const int j0 = __builtin_amdgcn_readfirstlane((tid >> 6) * RPT);
        int gc = tile_c0 + lane;
        if (gc > WW - 1) gc = WW - 1;       // clamped cols only feed discarded outputs

        const float* p1 = img1 + base;
        const float* p2 = img2 + base;

        // prefetch all 18 rows x 2 images into registers (36 loads in flight)
        float a[NR], b[NR];
        #pragma unroll
        for (int ri = 0; ri < NR; ++ri) {
            int gr = tile_r0 + j0 + ri;
            if (gr > HH - 1) gr = HH - 1;   // clamped rows feed discarded outputs
            const size_t ro = (size_t)gr * WW;   // wave-uniform -> SGPR
            a[ri] = p1[ro + gc];
            b[ri] = p2[ro + gc];
        }

        float accv[5][RPT];
        #pragma unroll
        for (int ch = 0; ch < 5; ++ch)
            #pragma unroll
            for (int j = 0; j < RPT; ++j) accv[ch][j] = 0.f;

        #pragma unroll
        for (int ri = 0; ri < NR; ++ri) {
            float av = a[ri], bv = b[ri];
            float aa = av * av, bb = bv * bv, ab = av * bv;
            #pragma unroll
            for (int j = 0; j < RPT; ++j) {
                int k = ri - j;
                if (k >= 0 && k < KS) {               // folds at compile time
                    float w = GW(k);
                    accv[0][j] += w * av;
                    accv[1][j] += w * bv;
                    accv[2][j] += w * aa;
                    accv[3][j] += w * bb;
                    accv[4][j] += w * ab;
                }
            }
        }
        if (lane < VW) {
            const int cb = lane * RS + j0;
            #pragma unroll
            for (int ch = 0; ch < 5; ++ch)
                #pragma unroll
                for (int j = 0; j < RPT; ++j)
                    vbuf[ch * CHS + cb + j] = accv[ch][j];
        }
    }
    __syncthreads();

    // ---------- phase 2: horizontal conv + SSIM ----------
    float lsum = 0.f;
    {
        const int r  = tid & 31;            // output row in tile
        const int c0 = (tid >> 5) * CPT;    // first output col (0..49)

        float acco[5][CPT];
        #pragma unroll
        for (int ch = 0; ch < 5; ++ch)
            #pragma unroll
            for (int j = 0; j < CPT; ++j) acco[ch][j] = 0.f;

        #pragma unroll
        for (int ch = 0; ch < 5; ++ch) {
            const float* vp = &vbuf[ch * CHS + r];
            #pragma unroll
            for (int i = 0; i < CPT + KS - 1; ++i) {  // 17 positions
                int ci = c0 + i;
                if (i >= 13) ci = (ci > VW - 1) ? VW - 1 : ci;  // only last col-group
                float v = vp[ci * RS];                // lanes r=0..31 -> consecutive addrs
                #pragma unroll
                for (int j = 0; j < CPT; ++j) {
                    int k = i - j;
                    if (k >= 0 && k < KS)             // folds at compile time
                        acco[ch][j] += GW(k) * v;
                }
            }
        }

        const float c1 = 1e-4f, c2 = 9e-4f;           // L = 1 for [0,1) inputs
        const int orow = tile_r0 + r;
        #pragma unroll
        for (int j = 0; j < CPT; ++j) {
            int lc = c0 + j, ocol = tile_c0 + lc;
            if (lc < OTW && ocol < WO && orow < HO) {
                float mu1 = acco[0][j], mu2 = acco[1][j];
                float e11 = acco[2][j], e22 = acco[3][j], e12 = acco[4][j];
                float mu1s = mu1 * mu1, mu2s = mu2 * mu2, mu12 = mu1 * mu2;
                float sg1 = e11 - mu1s, sg2 = e22 - mu2s, sg12 = e12 - mu12;
                float num = (2.f * mu12 + c1) * (2.f * sg12 + c2);
                float den = (mu1s + mu2s + c1) * (sg1 + sg2 + c2);
                lsum += num * __builtin_amdgcn_rcpf(den);
            }
        }
    }

    // ---------- reduction ----------
    #pragma unroll
    for (int off = 32; off; off >>= 1)
        lsum += __shfl_down(lsum, off, 64);
    __syncthreads();                      // vbuf reads done -> reuse for partials
    if ((tid & 63) == 0) vbuf[tid >> 6] = lsum;
    __syncthreads();
    if (tid == 0) {
        double t = (double)vbuf[0] + (double)vbuf[1] +
                   (double)vbuf[2] + (double)vbuf[3];
        atomicAdd(acc, t);
    }
}

__global__ void ssim_finalize(const double* __restrict__ acc,
                              float* __restrict__ out)
{
    out[0] = (float)(acc[0] / (double)(16LL * 3LL * (long long)HO * (long long)WO));
}

extern "C" void kernel_launch(void* const* d_in, const int* in_sizes, int n_in,
                              void* d_out, int out_size, void* d_ws, size_t ws_size,
                              hipStream_t stream) {
    const float* img1 = (const float*)d_in[0];
    const float* img2 = (const float*)d_in[1];
    const float* win  = (const float*)d_in[2];  // (3,1,11,11); channels identical
    float* out = (float*)d_out;
    double* acc = (double*)d_ws;

    hipMemsetAsync(acc, 0, sizeof(double), stream);

    dim3 grid((WO + OTW - 1) / OTW, (HO + OTH - 1) / OTH, 16 * 3);
    ssim_sep_kernel<<<grid, 256, 0, stream>>>(img1, img2, win, acc);
    ssim_finalize<<<1, 1, 0, stream>>>(acc, out);
}